// Round 8
// baseline (482.678 us; speedup 1.0000x reference)
//
#include <hip/hip_runtime.h>
#include <math.h>

typedef float f4 __attribute__((ext_vector_type(4)));

static __device__ __forceinline__ void stnt(float* p, f4 v) {
    __builtin_nontemporal_store(v, (f4*)p);
}

// x: [B=4][A=64][S=64][C=64][F=64] fp32.
// out = x * att_c[b,c,f] * att_s[b,s,f] * att_a[b,a,f]
//
// Single persistent kernel, 4 phases split by a manual device-scope barrier.
// grid = 1024 hardcoded; __launch_bounds__(256,4) forces VGPR<=128 so 4
// blocks/CU co-residency is guaranteed (LDS 19.5 KiB < 40 KiB/block).
// R7 proved the L3 keeps x resident between pool and scale (FETCH 276 MB);
// R7's slowness was the failed occupancy query -> grid 256 (1 blk/CU).

static __device__ __forceinline__ void gbar(unsigned* cnt, unsigned* rel,
                                            unsigned nblk, unsigned phase) {
    __syncthreads();
    if (threadIdx.x == 0) {
        __threadfence();   // agent release
        unsigned prev = __hip_atomic_fetch_add(cnt, 1u, __ATOMIC_ACQ_REL,
                                               __HIP_MEMORY_SCOPE_AGENT);
        if (prev == nblk * phase - 1u) {
            __hip_atomic_store(rel, phase, __ATOMIC_RELEASE,
                               __HIP_MEMORY_SCOPE_AGENT);
        } else {
            while (__hip_atomic_load(rel, __ATOMIC_ACQUIRE,
                                     __HIP_MEMORY_SCOPE_AGENT) < phase)
                __builtin_amdgcn_s_sleep(2);
        }
        __threadfence();   // agent acquire
    }
    __syncthreads();
}

__global__ __launch_bounds__(256, 4) void fused_kernel(
    const float* __restrict__ x,
    const float* __restrict__ w1_a, const float* __restrict__ w1_s, const float* __restrict__ w1_c,
    const float* __restrict__ w2_a, const float* __restrict__ w2_s, const float* __restrict__ w2_c,
    float* __restrict__ out,
    float* __restrict__ ps, float* __restrict__ pc,
    float* __restrict__ m_a, float* __restrict__ m_s, float* __restrict__ m_c,
    float* __restrict__ att_a, float* __restrict__ att_s, float* __restrict__ att_c,
    unsigned* __restrict__ bar)
{
    __shared__ float shl[4864];           // 19 KiB, re-purposed per phase
    const int t = threadIdx.x;
    const unsigned nblk = gridDim.x;      // 1024
    unsigned* cnt = bar;
    unsigned* rel = bar + 32;

    // ---------------- phase 1: pool (low-VGPR layout) ----------------
    // wave w = c-quarter; lane = (sg:2b s-subgroup, fg:4b f4-column).
    // Per c-row j: r-loop completes the 16-s chunk sum -> 2 shuffles over sg
    // -> direct 256 B store to pc. Only ssum[4] stays live across j.
    {
        const int w  = t >> 6;
        const int lane = t & 63;
        const int sg = lane >> 4;
        const int fg = lane & 15;

        for (unsigned vb = blockIdx.x; vb < 1024; vb += nblk) {
            const int q = vb & 3, ba = vb >> 2;
            const float* xa = x + (size_t)ba * 262144
                            + (size_t)(q * 16 + sg * 4) * 4096 + fg * 4;

            f4 ssum[4];
#pragma unroll
            for (int r = 0; r < 4; ++r) ssum[r] = f4{0.f, 0.f, 0.f, 0.f};

#pragma unroll 4
            for (int j = 0; j < 16; ++j) {
                const int c = w * 16 + j;
                const float* xc = xa + c * 64;
                f4 cs = f4{0.f, 0.f, 0.f, 0.f};
#pragma unroll
                for (int r = 0; r < 4; ++r) {
                    f4 v = *(const f4*)(xc + r * 4096);
                    ssum[r] += v;
                    cs += v;
                }
                // sum over the 16 s of this chunk: fold sg lanes (bits 4,5)
#pragma unroll
                for (int i = 0; i < 4; ++i) cs[i] += __shfl_xor(cs[i], 16);
#pragma unroll
                for (int i = 0; i < 4; ++i) cs[i] += __shfl_xor(cs[i], 32);
                if (sg == 0)
                    *(f4*)(pc + (size_t)vb * 4096 + c * 64 + fg * 4) = cs;
            }

            // ps: merge the 4 waves' c-quarter partials (4 KiB LDS)
            __syncthreads();              // guard shl reuse across vb iters
#pragma unroll
            for (int r = 0; r < 4; ++r)
                *(f4*)(&shl[w * 1024 + (sg * 4 + r) * 64 + fg * 4]) = ssum[r];
            __syncthreads();
            {
                const int sl = t >> 4, f2 = (t & 15) * 4;
                f4 acc = *(const f4*)(&shl[sl * 64 + f2]);
#pragma unroll
                for (int w2 = 1; w2 < 4; ++w2)
                    acc += *(const f4*)(&shl[w2 * 1024 + sl * 64 + f2]);
                *(f4*)(ps + (size_t)ba * 4096 + (q * 16 + sl) * 64 + f2) = acc;
            }
        }
    }
    gbar(cnt, rel, nblk, 1);

    // ---------------- phase 2: reduce ----------------
    {
        const int g = t >> 6, f = t & 63;
        float (*sm)[64] = (float(*)[64])shl;
        for (unsigned vb = blockIdx.x; vb < 768; vb += nblk) {
            const int region = vb >> 8;
            const int b = (vb >> 6) & 3;
            const int d = vb & 63;
            float acc = 0.f;
            if (region == 0) {
#pragma unroll 8
                for (int i = g; i < 256; i += 4)
                    acc += pc[(size_t)(b * 256 + i) * 4096 + d * 64 + f];
            } else if (region == 1) {
#pragma unroll 8
                for (int i = g; i < 64; i += 4)          // m_s: sum over a
                    acc += ps[((size_t)(b * 64 + i) * 64 + d) * 64 + f];
            } else {
#pragma unroll 8
                for (int i = g; i < 64; i += 4)          // m_a: sum over s
                    acc += ps[((size_t)(b * 64 + d) * 64 + i) * 64 + f];
            }
            __syncthreads();
            sm[g][f] = acc;
            __syncthreads();
            if (t < 64) {
                float tot = (sm[0][t] + sm[1][t] + sm[2][t] + sm[3][t]) * (1.f / 4096.f);
                float* dst = region == 0 ? m_c : (region == 1 ? m_s : m_a);
                dst[((size_t)b * 64 + d) * 64 + t] = tot;
            }
        }
    }
    gbar(cnt, rel, nblk, 2);

    // ---------------- phase 3: attn ----------------
    {
        float* w1ld = shl;                 // 1024
        float* w2ld = shl + 1024;          // 1024
        float (*mld)[64] = (float(*)[64])(shl + 2048);   // 4*64
        float (*zld)[16] = (float(*)[16])(shl + 2304);   // 4*16
        for (unsigned vb = blockIdx.x; vb < 192; vb += nblk) {
            const int axis = vb >> 6;
            const int f    = vb & 63;
            const float* m  = axis == 0 ? m_a  : (axis == 1 ? m_s  : m_c);
            const float* w1 = axis == 0 ? w1_a : (axis == 1 ? w1_s : w1_c);
            const float* w2 = axis == 0 ? w2_a : (axis == 1 ? w2_s : w2_c);
            float* att      = axis == 0 ? att_a : (axis == 1 ? att_s : att_c);

            __syncthreads();
            if (t < 64) {
                const f4* s1 = (const f4*)(w1 + (size_t)f * 1024);
                const f4* s2 = (const f4*)(w2 + (size_t)f * 1024);
#pragma unroll
                for (int i = 0; i < 4; ++i) {
                    ((f4*)w1ld)[t + 64 * i] = s1[t + 64 * i];
                    ((f4*)w2ld)[t + 64 * i] = s2[t + 64 * i];
                }
#pragma unroll
                for (int bb = 0; bb < 4; ++bb)
                    mld[bb][t] = m[((size_t)bb * 64 + t) * 64 + f];
            }
            __syncthreads();
            if (t < 64) {
                const int bb = t >> 4, e = t & 15;
                float acc = 0.f;
#pragma unroll
                for (int dd = 0; dd < 64; ++dd) acc += mld[bb][dd] * w1ld[dd * 16 + e];
                zld[bb][e] = fmaxf(acc, 0.f);
            }
            __syncthreads();
            if (t < 64) {
#pragma unroll
                for (int bb = 0; bb < 4; ++bb) {
                    float acc = 0.f;
#pragma unroll
                    for (int e = 0; e < 16; ++e) acc += zld[bb][e] * w2ld[e * 64 + t];
                    att[((size_t)bb * 64 + t) * 64 + f] = 1.f / (1.f + expf(-acc));
                }
            }
        }
    }
    gbar(cnt, rel, nblk, 3);

    // ---------------- phase 4: scale (x mostly L3-resident) ----------------
    {
        const int fg = t & 15;
        const int cq = t >> 4;
        float (*acl)[68] = (float(*)[68])shl;            // 64*68 = 4352
        float (*asl)[64] = (float(*)[64])(shl + 4352);   // 8*64  = 512

        for (unsigned u = blockIdx.x; u < 2048; u += nblk) {
            const int so = u & 7;
            const int a  = (u >> 3) & 63;
            const int b  = u >> 9;

            __syncthreads();
            {
                const f4* srcc = (const f4*)(att_c + (size_t)b * 4096);
#pragma unroll
                for (int i = 0; i < 4; ++i) {
                    int qq = t + 256 * i;          // f4 id: c = qq>>4, f = (qq&15)*4
                    f4 v = srcc[qq];
                    *(f4*)(&acl[qq >> 4][(qq & 15) * 4]) = v;
                }
                if (t < 128) {
                    f4 v = *(const f4*)(att_s + (size_t)b * 4096 + so * 512 + t * 4);
                    *(f4*)(&asl[t >> 4][(t & 15) * 4]) = v;
                }
            }
            f4 aa = *(const f4*)(att_a + (size_t)b * 4096 + a * 64 + fg * 4);
            __syncthreads();

            f4 acv[4];
#pragma unroll
            for (int k = 0; k < 4; ++k)
                acv[k] = *(const f4*)(&acl[k * 16 + cq][fg * 4]);

            const size_t base = (size_t)(b * 4096 + a * 64 + so * 8) * 4096;
            const float* xs = x + base;
            float* os = out + base;

            for (int sl = 0; sl < 8; ++sl) {
                f4 m0 = aa * *(const f4*)(&asl[sl][fg * 4]);
#pragma unroll
                for (int k = 0; k < 4; ++k) {
                    const int c = k * 16 + cq;
                    const size_t off = (size_t)(sl * 64 + c) * 64 + fg * 4;
                    f4 v = *(const f4*)(xs + off);
                    stnt(os + off, v * m0 * acv[k]);
                }
            }
        }
    }
}

extern "C" void kernel_launch(void* const* d_in, const int* in_sizes, int n_in,
                              void* d_out, int out_size, void* d_ws, size_t ws_size,
                              hipStream_t stream)
{
    (void)in_sizes; (void)n_in; (void)out_size; (void)ws_size;
    const float* x    = (const float*)d_in[0];
    const float* w1_a = (const float*)d_in[1];
    const float* w1_s = (const float*)d_in[2];
    const float* w1_c = (const float*)d_in[3];
    const float* w2_a = (const float*)d_in[4];
    const float* w2_s = (const float*)d_in[5];
    const float* w2_c = (const float*)d_in[6];
    float* out = (float*)d_out;

    // Workspace layout (fully rewritten each call before being read):
    float* ps    = (float*)d_ws;            // [4][64][64][64]   4 MiB
    float* pc    = ps + 1048576;            // [1024][64][64]   16 MiB
    float* m_a   = pc + 4194304;            // [4][64][64]      64 KiB each
    float* m_s   = m_a + 16384;
    float* m_c   = m_s + 16384;
    float* att_a = m_c + 16384;
    float* att_s = att_a + 16384;
    float* att_c = att_s + 16384;
    unsigned* bar = (unsigned*)(att_c + 16384);   // cnt @+0, rel @+32 words

    // Zero barrier state every call (async, capture-safe).
    hipMemsetAsync((void*)bar, 0, 256, stream);

    // grid = 4 blocks/CU x 256 CUs; co-residency guaranteed by
    // __launch_bounds__(256,4) (VGPR<=128) + 19 KiB LDS (<40 KiB/block).
    hipLaunchKernelGGL(fused_kernel, dim3(1024), dim3(256), 0, stream,
                       x, w1_a, w1_s, w1_c, w2_a, w2_s, w2_c, out,
                       ps, pc, m_a, m_s, m_c, att_a, att_s, att_c, bar);
}

// Round 9
// 203.935 us; speedup vs baseline: 2.3668x; 2.3668x over previous
//
#include <hip/hip_runtime.h>
#include <math.h>

typedef float f4 __attribute__((ext_vector_type(4)));

static __device__ __forceinline__ void stnt(float* p, f4 v) {
    __builtin_nontemporal_store(v, (f4*)p);
}

// x: [B=4][A=64][S=64][C=64][F=64] fp32.
// out = x * att_c[b,c,f] * att_s[b,s,f] * att_a[b,a,f]
// 4 dispatches (R5 shape, 144.7us). Pool redesigned for max memory-level
// parallelism: 32 independent f4 loads per thread, no cross-lane ops in the
// hot loop (R8 lesson: 4-loads-then-shuffle-chain collapses to ~1 TB/s).

// ---------------- pool: grid 1024 = (ba, sq), block 512 (8 waves) ----------------
// Block covers slab ba, s in [sq*16, sq*16+16), all c, all f.
// wave w = c-octant (c = w*8+j); lane = (sg:2 | fg:4); s = sq*16 + sg*4 + r.
__global__ __launch_bounds__(512, 4) void pool_kernel(
    const float* __restrict__ x,
    float* __restrict__ ps,          // [ba][s][f]  (sum over c)      4 MiB
    float* __restrict__ pc)          // [ba*4+sq][c][f] (sum over 16 s) 16 MiB
{
    const int blk = blockIdx.x;
    const int sq = blk & 3;
    const int ba = blk >> 2;
    const int t  = threadIdx.x;
    const int w  = t >> 6;            // c-octant
    const int lane = t & 63;
    const int sg = lane >> 4;         // s-subgroup
    const int fg = lane & 15;         // f4 column

    const float* base = x + (size_t)ba * 262144
                      + (size_t)(sq * 16 + sg * 4) * 4096 + w * 8 * 64 + fg * 4;

    f4 csum[8];                       // per c=w*8+j, over this thread's 4 s
    f4 srow[4];                       // per s=r, over this thread's 8 c
#pragma unroll
    for (int j = 0; j < 8; ++j) csum[j] = f4{0.f, 0.f, 0.f, 0.f};
#pragma unroll
    for (int r = 0; r < 4; ++r) srow[r] = f4{0.f, 0.f, 0.f, 0.f};

    // hot loop: 32 independent 16-B loads, accumulate only
#pragma unroll
    for (int r = 0; r < 4; ++r) {
#pragma unroll
        for (int j = 0; j < 8; ++j) {
            f4 v = *(const f4*)(base + r * 4096 + j * 64);
            csum[j] += v;
            srow[r] += v;
        }
    }

    // ---- pc: fold csum over sg (lane bits 4,5), then sg==0 stores ----
#pragma unroll
    for (int j = 0; j < 8; ++j) {
#pragma unroll
        for (int i = 0; i < 4; ++i) csum[j][i] += __shfl_xor(csum[j][i], 16);
#pragma unroll
        for (int i = 0; i < 4; ++i) csum[j][i] += __shfl_xor(csum[j][i], 32);
    }
    if (sg == 0) {
        float* dst = pc + (size_t)blk * 4096 + w * 8 * 64 + fg * 4;
#pragma unroll
        for (int j = 0; j < 8; ++j)
            *(f4*)(dst + j * 64) = csum[j];
    }

    // ---- ps: one LDS stage (wave-private slices), one sync, 8-way merge ----
    __shared__ float lds[8192];       // [8 w][16 s][64 f] = 32 KiB
#pragma unroll
    for (int r = 0; r < 4; ++r)
        *(f4*)(&lds[w * 1024 + (sg * 4 + r) * 64 + fg * 4]) = srow[r];
    __syncthreads();
    if (t < 256) {
        const int sl = t >> 4, fq = (t & 15) * 4;
        f4 acc = *(const f4*)(&lds[sl * 64 + fq]);
#pragma unroll
        for (int w2 = 1; w2 < 8; ++w2)
            acc += *(const f4*)(&lds[w2 * 1024 + sl * 64 + fq]);
        *(f4*)(ps + (size_t)ba * 4096 + (sq * 16 + sl) * 64 + fq) = acc;
    }
}

// ---------------- reduce: grid 768 = region*256 + b*64 + d, block 256 ----------------
// region 0: m_c (heavy), 1: m_s, 2: m_a. Wave-coalesced 256 B rows, g-split.
__global__ __launch_bounds__(256) void reduce_kernel(
    const float* __restrict__ ps, const float* __restrict__ pc,
    float* __restrict__ m_a, float* __restrict__ m_s, float* __restrict__ m_c)
{
    const int blk = blockIdx.x;
    const int region = blk >> 8;
    const int b = (blk >> 6) & 3;
    const int d = blk & 63;
    const int t = threadIdx.x;
    const int g = t >> 6, f = t & 63;

    float acc = 0.f;
    if (region == 0) {
#pragma unroll 8
        for (int i = g; i < 256; i += 4)
            acc += pc[(size_t)(b * 256 + i) * 4096 + d * 64 + f];
    } else if (region == 1) {
#pragma unroll 8
        for (int i = g; i < 64; i += 4)          // m_s: sum over a
            acc += ps[((size_t)(b * 64 + i) * 64 + d) * 64 + f];
    } else {
#pragma unroll 8
        for (int i = g; i < 64; i += 4)          // m_a: sum over s
            acc += ps[((size_t)(b * 64 + d) * 64 + i) * 64 + f];
    }

    __shared__ float sm[4][64];
    sm[g][f] = acc;
    __syncthreads();
    if (t < 64) {
        float tot = (sm[0][t] + sm[1][t] + sm[2][t] + sm[3][t]) * (1.f / 4096.f);
        float* dst = region == 0 ? m_c : (region == 1 ? m_s : m_a);
        dst[((size_t)b * 64 + d) * 64 + t] = tot;
    }
}

// ---------------- attn: grid 192 = (axis,f), block 64, all 4 batches ----------------
__global__ __launch_bounds__(64) void attn_kernel(
    const float* __restrict__ m_a, const float* __restrict__ m_s, const float* __restrict__ m_c,
    const float* __restrict__ w1_a, const float* __restrict__ w1_s, const float* __restrict__ w1_c,
    const float* __restrict__ w2_a, const float* __restrict__ w2_s, const float* __restrict__ w2_c,
    float* __restrict__ att_a, float* __restrict__ att_s, float* __restrict__ att_c)
{
    const int axis = blockIdx.x >> 6;
    const int f    = blockIdx.x & 63;
    const float* m  = axis == 0 ? m_a  : (axis == 1 ? m_s  : m_c);
    const float* w1 = axis == 0 ? w1_a : (axis == 1 ? w1_s : w1_c);  // [F,64,16]
    const float* w2 = axis == 0 ? w2_a : (axis == 1 ? w2_s : w2_c);  // [F,16,64]
    float* att      = axis == 0 ? att_a : (axis == 1 ? att_s : att_c);

    __shared__ float w1ld[1024];
    __shared__ float w2ld[1024];
    __shared__ float mld[4][64];
    __shared__ float zld[4][16];
    const int t = threadIdx.x;

    {
        const f4* s1 = (const f4*)(w1 + (size_t)f * 1024);
        const f4* s2 = (const f4*)(w2 + (size_t)f * 1024);
#pragma unroll
        for (int i = 0; i < 4; ++i) {
            ((f4*)w1ld)[t + 64 * i] = s1[t + 64 * i];
            ((f4*)w2ld)[t + 64 * i] = s2[t + 64 * i];
        }
#pragma unroll
        for (int bb = 0; bb < 4; ++bb)
            mld[bb][t] = m[((size_t)bb * 64 + t) * 64 + f];
    }
    __syncthreads();
    {
        const int bb = t >> 4, e = t & 15;       // 4 b x 16 e = 64 threads
        float acc = 0.f;
#pragma unroll
        for (int dd = 0; dd < 64; ++dd) acc += mld[bb][dd] * w1ld[dd * 16 + e];
        zld[bb][e] = fmaxf(acc, 0.f);
    }
    __syncthreads();
#pragma unroll
    for (int bb = 0; bb < 4; ++bb) {
        float acc = 0.f;
#pragma unroll
        for (int e = 0; e < 16; ++e) acc += zld[bb][e] * w2ld[e * 64 + t];
        att[((size_t)bb * 64 + t) * 64 + f] = 1.f / (1.f + expf(-acc));
    }
}

// ---------------- scale: grid 2048 (reversed), block 256 ----------------
__global__ __launch_bounds__(256) void scale_kernel(
    const float* __restrict__ x,
    const float* __restrict__ att_a, const float* __restrict__ att_s,
    const float* __restrict__ att_c,
    float* __restrict__ out)
{
    const int blk = 2047 - blockIdx.x;  // start at b=3: tail of pool's read stream
    const int so = blk & 7;
    const int a  = (blk >> 3) & 63;
    const int b  = blk >> 9;
    const int t  = threadIdx.x;
    const int fg = t & 15;
    const int cq = t >> 4;

    __shared__ float acl[64][68];   // +4 pad: conflict-free column reads
    __shared__ float asl[8][64];

    {
        const f4* srcc = (const f4*)(att_c + (size_t)b * 4096);
#pragma unroll
        for (int i = 0; i < 4; ++i) {
            int qq = t + 256 * i;                 // f4 id: c = qq>>4, f = (qq&15)*4
            f4 v = srcc[qq];
            *(f4*)(&acl[qq >> 4][(qq & 15) * 4]) = v;
        }
        if (t < 128) {
            f4 v = *(const f4*)(att_s + (size_t)b * 4096 + so * 512 + t * 4);
            *(f4*)(&asl[t >> 4][(t & 15) * 4]) = v;
        }
    }
    f4 aa = *(const f4*)(att_a + (size_t)b * 4096 + a * 64 + fg * 4);
    __syncthreads();

    f4 acv[4];
#pragma unroll
    for (int k = 0; k < 4; ++k)
        acv[k] = *(const f4*)(&acl[k * 16 + cq][fg * 4]);

    const size_t base = (size_t)(b * 4096 + a * 64 + so * 8) * 4096;
    const float* xs = x + base;
    float* os = out + base;

    for (int sl = 0; sl < 8; ++sl) {
        f4 m0 = aa * *(const f4*)(&asl[sl][fg * 4]);
#pragma unroll
        for (int k = 0; k < 4; ++k) {
            const int c = k * 16 + cq;
            const size_t off = (size_t)(sl * 64 + c) * 64 + fg * 4;
            f4 v = *(const f4*)(xs + off);
            stnt(os + off, v * m0 * acv[k]);
        }
    }
}

extern "C" void kernel_launch(void* const* d_in, const int* in_sizes, int n_in,
                              void* d_out, int out_size, void* d_ws, size_t ws_size,
                              hipStream_t stream)
{
    (void)in_sizes; (void)n_in; (void)out_size; (void)ws_size;
    const float* x    = (const float*)d_in[0];
    const float* w1_a = (const float*)d_in[1];
    const float* w1_s = (const float*)d_in[2];
    const float* w1_c = (const float*)d_in[3];
    const float* w2_a = (const float*)d_in[4];
    const float* w2_s = (const float*)d_in[5];
    const float* w2_c = (const float*)d_in[6];
    float* out = (float*)d_out;

    // Workspace layout (all fully rewritten each call before being read):
    float* ps    = (float*)d_ws;            // [4][64][64][64]   4 MiB
    float* pc    = ps + 1048576;            // [1024][64][64]   16 MiB
    float* m_a   = pc + 4194304;            // [4][64][64]      64 KiB each
    float* m_s   = m_a + 16384;
    float* m_c   = m_s + 16384;
    float* att_a = m_c + 16384;
    float* att_s = att_a + 16384;
    float* att_c = att_s + 16384;

    hipLaunchKernelGGL(pool_kernel,   dim3(1024), dim3(512), 0, stream, x, ps, pc);
    hipLaunchKernelGGL(reduce_kernel, dim3(768),  dim3(256), 0, stream,
                       ps, pc, m_a, m_s, m_c);
    hipLaunchKernelGGL(attn_kernel,   dim3(192),  dim3(64),  0, stream,
                       m_a, m_s, m_c, w1_a, w1_s, w1_c, w2_a, w2_s, w2_c,
                       att_a, att_s, att_c);
    hipLaunchKernelGGL(scale_kernel,  dim3(2048), dim3(256), 0, stream,
                       x, att_a, att_s, att_c, out);
}

// Round 10
// 146.412 us; speedup vs baseline: 3.2967x; 1.3929x over previous
//
#include <hip/hip_runtime.h>
#include <math.h>

typedef float f4 __attribute__((ext_vector_type(4)));

static __device__ __forceinline__ void stnt(float* p, f4 v) {
    __builtin_nontemporal_store(v, (f4*)p);
}

// async global->LDS, 16 B per lane, linear dest (base + lane*16)
static __device__ __forceinline__ void gll16(const float* g, float* l) {
    __builtin_amdgcn_global_load_lds(
        (__attribute__((address_space(1))) void*)(uintptr_t)(const void*)g,
        (__attribute__((address_space(3))) void*)l,
        16, 0, 0);
}

// x: [B=4][A=64][S=64][C=64][F=64] fp32.
// out = x * att_c[b,c,f] * att_s[b,s,f] * att_a[b,a,f]
//
// R10 pool: LDS-staged via global_load_lds (no dest VGPRs, fire-and-forget
// stream), both reductions read the tile from LDS -> zero shuffles, ~45 VGPR,
// 36 KiB LDS -> 4 blocks/CU. R1/R5/R8/R9 lesson: VGPR-accumulate pools with
// shuffles in the stream cap at 1-3.5 TB/s.

// ---------------- pool: grid 1024 = (ba, q), block 256 (4 waves) ----------------
// Block: slab ba, s-quarter q (16 s). 8 tiles of 2 s (32 KiB each).
__global__ __launch_bounds__(256) void pool_kernel(
    const float* __restrict__ x,
    float* __restrict__ ps,          // [ba][s][f]  (sum over c)       4 MiB
    float* __restrict__ pc)          // [ba*4+q][c][f] (sum over 16 s) 16 MiB
{
    const int blk = blockIdx.x;      // ba*4 + q
    const int q  = blk & 3;
    const int ba = blk >> 2;
    const int t  = threadIdx.x;
    const int w  = t >> 6, lane = t & 63;

    __shared__ __align__(16) float tile[8192];   // 2 s x 64 c x 64 f = 32 KiB
    __shared__ __align__(16) float scr[1024];    // [2 sl][8 cg][16 fg] f4 = 4 KiB

    // pc: thread (ch, fgp) owns c = ch*4+k, k=0..3
    const int ch = t >> 4, fgp = t & 15;
    f4 csum[4];
#pragma unroll
    for (int k = 0; k < 4; ++k) csum[k] = f4{0.f, 0.f, 0.f, 0.f};

    // ps-partial ids
    const int sl = t >> 7;            // s within tile
    const int cg = (t >> 4) & 7;      // 8-c group
    const int fgs = t & 15;

    const float* gbase = x + (size_t)ba * 262144 + (size_t)(q * 16) * 4096;

    for (int tl = 0; tl < 8; ++tl) {
        const float* gt = gbase + tl * 8192;
        // stage 32 KiB: 4 waves x 8 issues x 1 KiB, LDS linear = global linear
#pragma unroll
        for (int i = 0; i < 8; ++i) {
            const int o = (w * 8 + i) * 256;     // float offset of 1-KiB chunk
            gll16(gt + o + lane * 4, tile + o);
        }
        asm volatile("s_waitcnt vmcnt(0)" ::: "memory");
        __syncthreads();

        // ps partial: sum 8 c's for (sl, fgs) -> scratch
        {
            f4 p = f4{0.f, 0.f, 0.f, 0.f};
#pragma unroll
            for (int j = 0; j < 8; ++j)
                p += *(const f4*)(tile + sl * 4096 + (cg * 8 + j) * 64 + fgs * 4);
            *(f4*)(scr + ((sl * 8 + cg) * 16 + fgs) * 4) = p;
        }
        // pc accumulate: both s of the tile into csum (c fixed per thread)
#pragma unroll
        for (int k = 0; k < 4; ++k) {
            const int c = ch * 4 + k;
            csum[k] += *(const f4*)(tile + c * 64 + fgp * 4);
            csum[k] += *(const f4*)(tile + 4096 + c * 64 + fgp * 4);
        }
        __syncthreads();

        // finalize ps rows of this tile (reads scr only -> no hazard with the
        // next tile's staging; sync1 of the next iteration orders scr reuse)
        if (t < 32) {
            const int s2 = t >> 4, ff = t & 15;
            f4 acc = f4{0.f, 0.f, 0.f, 0.f};
#pragma unroll
            for (int g2 = 0; g2 < 8; ++g2)
                acc += *(const f4*)(scr + ((s2 * 8 + g2) * 16 + ff) * 4);
            *(f4*)(ps + (size_t)ba * 4096 + (q * 16 + tl * 2 + s2) * 64 + ff * 4) = acc;
        }
    }

    // store pc chunk
    float* dst = pc + (size_t)blk * 4096;
#pragma unroll
    for (int k = 0; k < 4; ++k)
        *(f4*)(dst + (ch * 4 + k) * 64 + fgp * 4) = csum[k];
}

// ---------------- reduce: grid 768 = region*256 + b*64 + d, block 256 ----------------
// region 0: m_c (heavy), 1: m_s, 2: m_a. Wave-coalesced 256 B rows, g-split.
__global__ __launch_bounds__(256) void reduce_kernel(
    const float* __restrict__ ps, const float* __restrict__ pc,
    float* __restrict__ m_a, float* __restrict__ m_s, float* __restrict__ m_c)
{
    const int blk = blockIdx.x;
    const int region = blk >> 8;
    const int b = (blk >> 6) & 3;
    const int d = blk & 63;
    const int t = threadIdx.x;
    const int g = t >> 6, f = t & 63;

    float acc = 0.f;
    if (region == 0) {
#pragma unroll 8
        for (int i = g; i < 256; i += 4)
            acc += pc[(size_t)(b * 256 + i) * 4096 + d * 64 + f];
    } else if (region == 1) {
#pragma unroll 8
        for (int i = g; i < 64; i += 4)          // m_s: sum over a
            acc += ps[((size_t)(b * 64 + i) * 64 + d) * 64 + f];
    } else {
#pragma unroll 8
        for (int i = g; i < 64; i += 4)          // m_a: sum over s
            acc += ps[((size_t)(b * 64 + d) * 64 + i) * 64 + f];
    }

    __shared__ float sm[4][64];
    sm[g][f] = acc;
    __syncthreads();
    if (t < 64) {
        float tot = (sm[0][t] + sm[1][t] + sm[2][t] + sm[3][t]) * (1.f / 4096.f);
        float* dst = region == 0 ? m_c : (region == 1 ? m_s : m_a);
        dst[((size_t)b * 64 + d) * 64 + t] = tot;
    }
}

// ---------------- attn: grid 192 = (axis,f), block 64, all 4 batches ----------------
__global__ __launch_bounds__(64) void attn_kernel(
    const float* __restrict__ m_a, const float* __restrict__ m_s, const float* __restrict__ m_c,
    const float* __restrict__ w1_a, const float* __restrict__ w1_s, const float* __restrict__ w1_c,
    const float* __restrict__ w2_a, const float* __restrict__ w2_s, const float* __restrict__ w2_c,
    float* __restrict__ att_a, float* __restrict__ att_s, float* __restrict__ att_c)
{
    const int axis = blockIdx.x >> 6;
    const int f    = blockIdx.x & 63;
    const float* m  = axis == 0 ? m_a  : (axis == 1 ? m_s  : m_c);
    const float* w1 = axis == 0 ? w1_a : (axis == 1 ? w1_s : w1_c);  // [F,64,16]
    const float* w2 = axis == 0 ? w2_a : (axis == 1 ? w2_s : w2_c);  // [F,16,64]
    float* att      = axis == 0 ? att_a : (axis == 1 ? att_s : att_c);

    __shared__ float w1ld[1024];
    __shared__ float w2ld[1024];
    __shared__ float mld[4][64];
    __shared__ float zld[4][16];
    const int t = threadIdx.x;

    {
        const f4* s1 = (const f4*)(w1 + (size_t)f * 1024);
        const f4* s2 = (const f4*)(w2 + (size_t)f * 1024);
#pragma unroll
        for (int i = 0; i < 4; ++i) {
            ((f4*)w1ld)[t + 64 * i] = s1[t + 64 * i];
            ((f4*)w2ld)[t + 64 * i] = s2[t + 64 * i];
        }
#pragma unroll
        for (int bb = 0; bb < 4; ++bb)
            mld[bb][t] = m[((size_t)bb * 64 + t) * 64 + f];
    }
    __syncthreads();
    {
        const int bb = t >> 4, e = t & 15;       // 4 b x 16 e = 64 threads
        float acc = 0.f;
#pragma unroll
        for (int dd = 0; dd < 64; ++dd) acc += mld[bb][dd] * w1ld[dd * 16 + e];
        zld[bb][e] = fmaxf(acc, 0.f);
    }
    __syncthreads();
#pragma unroll
    for (int bb = 0; bb < 4; ++bb) {
        float acc = 0.f;
#pragma unroll
        for (int e = 0; e < 16; ++e) acc += zld[bb][e] * w2ld[e * 64 + t];
        att[((size_t)bb * 64 + t) * 64 + f] = 1.f / (1.f + expf(-acc));
    }
}

// ---------------- scale: grid 2048 (reversed), block 256 ----------------
__global__ __launch_bounds__(256) void scale_kernel(
    const float* __restrict__ x,
    const float* __restrict__ att_a, const float* __restrict__ att_s,
    const float* __restrict__ att_c,
    float* __restrict__ out)
{
    const int blk = 2047 - blockIdx.x;  // start at b=3: tail of pool's read stream
    const int so = blk & 7;
    const int a  = (blk >> 3) & 63;
    const int b  = blk >> 9;
    const int t  = threadIdx.x;
    const int fg = t & 15;
    const int cq = t >> 4;

    __shared__ float acl[64][68];   // +4 pad: conflict-free column reads
    __shared__ float asl[8][64];

    {
        const f4* srcc = (const f4*)(att_c + (size_t)b * 4096);
#pragma unroll
        for (int i = 0; i < 4; ++i) {
            int qq = t + 256 * i;                 // f4 id: c = qq>>4, f = (qq&15)*4
            f4 v = srcc[qq];
            *(f4*)(&acl[qq >> 4][(qq & 15) * 4]) = v;
        }
        if (t < 128) {
            f4 v = *(const f4*)(att_s + (size_t)b * 4096 + so * 512 + t * 4);
            *(f4*)(&asl[t >> 4][(t & 15) * 4]) = v;
        }
    }
    f4 aa = *(const f4*)(att_a + (size_t)b * 4096 + a * 64 + fg * 4);
    __syncthreads();

    f4 acv[4];
#pragma unroll
    for (int k = 0; k < 4; ++k)
        acv[k] = *(const f4*)(&acl[k * 16 + cq][fg * 4]);

    const size_t base = (size_t)(b * 4096 + a * 64 + so * 8) * 4096;
    const float* xs = x + base;
    float* os = out + base;

    for (int sl = 0; sl < 8; ++sl) {
        f4 m0 = aa * *(const f4*)(&asl[sl][fg * 4]);
#pragma unroll
        for (int k = 0; k < 4; ++k) {
            const int c = k * 16 + cq;
            const size_t off = (size_t)(sl * 64 + c) * 64 + fg * 4;
            f4 v = *(const f4*)(xs + off);
            stnt(os + off, v * m0 * acv[k]);
        }
    }
}

extern "C" void kernel_launch(void* const* d_in, const int* in_sizes, int n_in,
                              void* d_out, int out_size, void* d_ws, size_t ws_size,
                              hipStream_t stream)
{
    (void)in_sizes; (void)n_in; (void)out_size; (void)ws_size;
    const float* x    = (const float*)d_in[0];
    const float* w1_a = (const float*)d_in[1];
    const float* w1_s = (const float*)d_in[2];
    const float* w1_c = (const float*)d_in[3];
    const float* w2_a = (const float*)d_in[4];
    const float* w2_s = (const float*)d_in[5];
    const float* w2_c = (const float*)d_in[6];
    float* out = (float*)d_out;

    // Workspace layout (all fully rewritten each call before being read):
    float* ps    = (float*)d_ws;            // [4][64][64][64]   4 MiB
    float* pc    = ps + 1048576;            // [1024][64][64]   16 MiB
    float* m_a   = pc + 4194304;            // [4][64][64]      64 KiB each
    float* m_s   = m_a + 16384;
    float* m_c   = m_s + 16384;
    float* att_a = m_c + 16384;
    float* att_s = att_a + 16384;
    float* att_c = att_s + 16384;

    hipLaunchKernelGGL(pool_kernel,   dim3(1024), dim3(256), 0, stream, x, ps, pc);
    hipLaunchKernelGGL(reduce_kernel, dim3(768),  dim3(256), 0, stream,
                       ps, pc, m_a, m_s, m_c);
    hipLaunchKernelGGL(attn_kernel,   dim3(192),  dim3(64),  0, stream,
                       m_a, m_s, m_c, w1_a, w1_s, w1_c, w2_a, w2_s, w2_c,
                       att_a, att_s, att_c);
    hipLaunchKernelGGL(scale_kernel,  dim3(2048), dim3(256), 0, stream,
                       x, att_a, att_s, att_c, out);
}

// Round 11
// 145.989 us; speedup vs baseline: 3.3063x; 1.0029x over previous
//
#include <hip/hip_runtime.h>
#include <math.h>

typedef float f4 __attribute__((ext_vector_type(4)));

static __device__ __forceinline__ void stnt(float* p, f4 v) {
    __builtin_nontemporal_store(v, (f4*)p);
}

// async global->LDS, 16 B per lane, linear dest (base + lane*16)
static __device__ __forceinline__ void gll16(const float* g, float* l) {
    __builtin_amdgcn_global_load_lds(
        (__attribute__((address_space(1))) void*)(uintptr_t)(const void*)g,
        (__attribute__((address_space(3))) void*)l,
        16, 0, 0);
}

// x: [B=4][A=64][S=64][C=64][F=64] fp32.
// out = x * att_c[b,c,f] * att_s[b,s,f] * att_a[b,a,f]
//
// R11 pool: wave-autonomous double-buffered gll stream, counted vmcnt(4),
// no barriers / no shuffles / no drain in the hot loop (m218: counted vmcnt
// vs drain-0 = +38-73%). Cross-wave merges only at block end.

// chunk CH = r*4+cg: r = s-row of wave (0..3), cg = c-quarter (0..3).
// LDS chunk layout = staged linear order: [c_local*64 + f], 4 KiB.
// consume read i gives lane l: c = cg*16 + i*4 + (l>>4), col (l&15)*4.
template<int CH, bool LAST>
__device__ __forceinline__ void chunk_step(
    const float* xa4, float* twave, int lane4,
    f4 (&pcsum)[4][4], f4 (&srow)[4])
{
    constexpr int r  = CH >> 2;
    constexpr int cg = CH & 3;
    constexpr int tb = CH & 1;
    if constexpr (!LAST) {
        constexpr int CN  = (CH + 1) & 15;
        constexpr int rn  = CN >> 2;
        constexpr int cgn = CN & 3;
        constexpr int tbn = CN & 1;
        const float* src = xa4 + rn * 4096 + cgn * 1024 + lane4;
        float* dst = twave + tbn * 1024;
#pragma unroll
        for (int i = 0; i < 4; ++i)
            gll16(src + i * 256, dst + i * 256);
        asm volatile("s_waitcnt vmcnt(4)" ::: "memory");
    } else {
        asm volatile("s_waitcnt vmcnt(0)" ::: "memory");
    }
    __builtin_amdgcn_sched_barrier(0);
    const float* b = twave + tb * 1024 + lane4;
#pragma unroll
    for (int i = 0; i < 4; ++i) {
        f4 v = *(const f4*)(b + i * 256);
        pcsum[cg][i] += v;
        srow[r] += v;
    }
}

// ---------------- pool: grid 1024 = (ba, q), block 256 (4 waves) ----------------
__global__ __launch_bounds__(256) void pool_kernel(
    const float* __restrict__ x,
    float* __restrict__ ps,          // [ba][s][f]  (sum over c)       4 MiB
    float* __restrict__ pc)          // [ba*4+q][c][f] (sum over 16 s) 16 MiB
{
    const int blk = blockIdx.x;      // ba*4 + q
    const int q  = blk & 3;
    const int ba = blk >> 2;
    const int t  = threadIdx.x;
    const int w  = t >> 6, lane = t & 63;
    const int cl = lane >> 4, fg = lane & 15;
    const int lane4 = lane * 4;

    __shared__ __align__(16) float tile[8192];   // [4 w][2 buf][1024] = 32 KiB
    float* twave = tile + w * 2048;

    const float* xa4 = x + (size_t)ba * 262144 + (size_t)(q * 16 + w * 4) * 4096;

    f4 pcsum[4][4];                  // [cg][i]: c = cg*16 + i*4 + cl
    f4 srow[4];                      // per s-row r (this wave's 4 rows)
#pragma unroll
    for (int a2 = 0; a2 < 4; ++a2) {
#pragma unroll
        for (int b2 = 0; b2 < 4; ++b2) pcsum[a2][b2] = f4{0.f, 0.f, 0.f, 0.f};
        srow[a2] = f4{0.f, 0.f, 0.f, 0.f};
    }

    // prologue: stage chunk 0
#pragma unroll
    for (int i = 0; i < 4; ++i)
        gll16(xa4 + i * 256 + lane4, twave + i * 256);

    chunk_step<0,  false>(xa4, twave, lane4, pcsum, srow);
    chunk_step<1,  false>(xa4, twave, lane4, pcsum, srow);
    chunk_step<2,  false>(xa4, twave, lane4, pcsum, srow);
    chunk_step<3,  false>(xa4, twave, lane4, pcsum, srow);
    chunk_step<4,  false>(xa4, twave, lane4, pcsum, srow);
    chunk_step<5,  false>(xa4, twave, lane4, pcsum, srow);
    chunk_step<6,  false>(xa4, twave, lane4, pcsum, srow);
    chunk_step<7,  false>(xa4, twave, lane4, pcsum, srow);
    chunk_step<8,  false>(xa4, twave, lane4, pcsum, srow);
    chunk_step<9,  false>(xa4, twave, lane4, pcsum, srow);
    chunk_step<10, false>(xa4, twave, lane4, pcsum, srow);
    chunk_step<11, false>(xa4, twave, lane4, pcsum, srow);
    chunk_step<12, false>(xa4, twave, lane4, pcsum, srow);
    chunk_step<13, false>(xa4, twave, lane4, pcsum, srow);
    chunk_step<14, false>(xa4, twave, lane4, pcsum, srow);
    chunk_step<15, true >(xa4, twave, lane4, pcsum, srow);

    // ---- ps: fold srow over cl (lane bits 4,5), cl==0 stores ----
#pragma unroll
    for (int r = 0; r < 4; ++r) {
#pragma unroll
        for (int i = 0; i < 4; ++i) {
            srow[r][i] += __shfl_xor(srow[r][i], 16);
            srow[r][i] += __shfl_xor(srow[r][i], 32);
        }
    }
    if (cl == 0) {
#pragma unroll
        for (int r = 0; r < 4; ++r)
            *(f4*)(ps + (size_t)ba * 4096 + (q * 16 + w * 4 + r) * 64 + fg * 4)
                = srow[r];
    }

    // ---- pc: 2-round cross-wave merge (c halves), reusing tile ----
#pragma unroll
    for (int h = 0; h < 2; ++h) {
        __syncthreads();             // prior tile use (stream / round h-1) done
#pragma unroll
        for (int cg2 = 0; cg2 < 2; ++cg2)
#pragma unroll
            for (int i = 0; i < 4; ++i)
                *(f4*)(tile + w * 2048 + (cg2 * 4 + i) * 256 + cl * 64 + fg * 4)
                    = pcsum[h * 2 + cg2][i];
        __syncthreads();
#pragma unroll
        for (int cc = 0; cc < 2; ++cc) {
            const int c_local = (t >> 4) * 2 + cc;       // 0..31
            f4 acc = f4{0.f, 0.f, 0.f, 0.f};
#pragma unroll
            for (int w2 = 0; w2 < 4; ++w2)
                acc += *(const f4*)(tile + w2 * 2048 + c_local * 64 + (t & 15) * 4);
            *(f4*)(pc + (size_t)blk * 4096 + (h * 32 + c_local) * 64 + (t & 15) * 4)
                = acc;
        }
    }
}

// ---------------- reduce: grid 768 = region*256 + b*64 + d, block 256 ----------------
__global__ __launch_bounds__(256) void reduce_kernel(
    const float* __restrict__ ps, const float* __restrict__ pc,
    float* __restrict__ m_a, float* __restrict__ m_s, float* __restrict__ m_c)
{
    const int blk = blockIdx.x;
    const int region = blk >> 8;
    const int b = (blk >> 6) & 3;
    const int d = blk & 63;
    const int t = threadIdx.x;
    const int g = t >> 6, f = t & 63;

    float acc = 0.f;
    if (region == 0) {
#pragma unroll 8
        for (int i = g; i < 256; i += 4)
            acc += pc[(size_t)(b * 256 + i) * 4096 + d * 64 + f];
    } else if (region == 1) {
#pragma unroll 8
        for (int i = g; i < 64; i += 4)          // m_s: sum over a
            acc += ps[((size_t)(b * 64 + i) * 64 + d) * 64 + f];
    } else {
#pragma unroll 8
        for (int i = g; i < 64; i += 4)          // m_a: sum over s
            acc += ps[((size_t)(b * 64 + d) * 64 + i) * 64 + f];
    }

    __shared__ float sm[4][64];
    sm[g][f] = acc;
    __syncthreads();
    if (t < 64) {
        float tot = (sm[0][t] + sm[1][t] + sm[2][t] + sm[3][t]) * (1.f / 4096.f);
        float* dst = region == 0 ? m_c : (region == 1 ? m_s : m_a);
        dst[((size_t)b * 64 + d) * 64 + t] = tot;
    }
}

// ---------------- attn: grid 192 = (axis,f), block 64, all 4 batches ----------------
__global__ __launch_bounds__(64) void attn_kernel(
    const float* __restrict__ m_a, const float* __restrict__ m_s, const float* __restrict__ m_c,
    const float* __restrict__ w1_a, const float* __restrict__ w1_s, const float* __restrict__ w1_c,
    const float* __restrict__ w2_a, const float* __restrict__ w2_s, const float* __restrict__ w2_c,
    float* __restrict__ att_a, float* __restrict__ att_s, float* __restrict__ att_c)
{
    const int axis = blockIdx.x >> 6;
    const int f    = blockIdx.x & 63;
    const float* m  = axis == 0 ? m_a  : (axis == 1 ? m_s  : m_c);
    const float* w1 = axis == 0 ? w1_a : (axis == 1 ? w1_s : w1_c);  // [F,64,16]
    const float* w2 = axis == 0 ? w2_a : (axis == 1 ? w2_s : w2_c);  // [F,16,64]
    float* att      = axis == 0 ? att_a : (axis == 1 ? att_s : att_c);

    __shared__ float w1ld[1024];
    __shared__ float w2ld[1024];
    __shared__ float mld[4][64];
    __shared__ float zld[4][16];
    const int t = threadIdx.x;

    {
        const f4* s1 = (const f4*)(w1 + (size_t)f * 1024);
        const f4* s2 = (const f4*)(w2 + (size_t)f * 1024);
#pragma unroll
        for (int i = 0; i < 4; ++i) {
            ((f4*)w1ld)[t + 64 * i] = s1[t + 64 * i];
            ((f4*)w2ld)[t + 64 * i] = s2[t + 64 * i];
        }
#pragma unroll
        for (int bb = 0; bb < 4; ++bb)
            mld[bb][t] = m[((size_t)bb * 64 + t) * 64 + f];
    }
    __syncthreads();
    {
        const int bb = t >> 4, e = t & 15;       // 4 b x 16 e = 64 threads
        float acc = 0.f;
#pragma unroll
        for (int dd = 0; dd < 64; ++dd) acc += mld[bb][dd] * w1ld[dd * 16 + e];
        zld[bb][e] = fmaxf(acc, 0.f);
    }
    __syncthreads();
#pragma unroll
    for (int bb = 0; bb < 4; ++bb) {
        float acc = 0.f;
#pragma unroll
        for (int e = 0; e < 16; ++e) acc += zld[bb][e] * w2ld[e * 64 + t];
        att[((size_t)bb * 64 + t) * 64 + f] = 1.f / (1.f + expf(-acc));
    }
}

// ---------------- scale: grid 2048 (reversed), block 256 ----------------
__global__ __launch_bounds__(256) void scale_kernel(
    const float* __restrict__ x,
    const float* __restrict__ att_a, const float* __restrict__ att_s,
    const float* __restrict__ att_c,
    float* __restrict__ out)
{
    const int blk = 2047 - blockIdx.x;  // start at b=3: tail of pool's read stream
    const int so = blk & 7;
    const int a  = (blk >> 3) & 63;
    const int b  = blk >> 9;
    const int t  = threadIdx.x;
    const int fg = t & 15;
    const int cq = t >> 4;

    __shared__ float acl[64][68];   // +4 pad: conflict-free column reads
    __shared__ float asl[8][64];

    {
        const f4* srcc = (const f4*)(att_c + (size_t)b * 4096);
#pragma unroll
        for (int i = 0; i < 4; ++i) {
            int qq = t + 256 * i;                 // f4 id: c = qq>>4, f = (qq&15)*4
            f4 v = srcc[qq];
            *(f4*)(&acl[qq >> 4][(qq & 15) * 4]) = v;
        }
        if (t < 128) {
            f4 v = *(const f4*)(att_s + (size_t)b * 4096 + so * 512 + t * 4);
            *(f4*)(&asl[t >> 4][(t & 15) * 4]) = v;
        }
    }
    f4 aa = *(const f4*)(att_a + (size_t)b * 4096 + a * 64 + fg * 4);
    __syncthreads();

    f4 acv[4];
#pragma unroll
    for (int k = 0; k < 4; ++k)
        acv[k] = *(const f4*)(&acl[k * 16 + cq][fg * 4]);

    const size_t base = (size_t)(b * 4096 + a * 64 + so * 8) * 4096;
    const float* xs = x + base;
    float* os = out + base;

    for (int sl = 0; sl < 8; ++sl) {
        f4 m0 = aa * *(const f4*)(&asl[sl][fg * 4]);
#pragma unroll
        for (int k = 0; k < 4; ++k) {
            const int c = k * 16 + cq;
            const size_t off = (size_t)(sl * 64 + c) * 64 + fg * 4;
            f4 v = *(const f4*)(xs + off);
            stnt(os + off, v * m0 * acv[k]);
        }
    }
}

extern "C" void kernel_launch(void* const* d_in, const int* in_sizes, int n_in,
                              void* d_out, int out_size, void* d_ws, size_t ws_size,
                              hipStream_t stream)
{
    (void)in_sizes; (void)n_in; (void)out_size; (void)ws_size;
    const float* x    = (const float*)d_in[0];
    const float* w1_a = (const float*)d_in[1];
    const float* w1_s = (const float*)d_in[2];
    const float* w1_c = (const float*)d_in[3];
    const float* w2_a = (const float*)d_in[4];
    const float* w2_s = (const float*)d_in[5];
    const float* w2_c = (const float*)d_in[6];
    float* out = (float*)d_out;

    // Workspace layout (all fully rewritten each call before being read):
    float* ps    = (float*)d_ws;            // [4][64][64][64]   4 MiB
    float* pc    = ps + 1048576;            // [1024][64][64]   16 MiB
    float* m_a   = pc + 4194304;            // [4][64][64]      64 KiB each
    float* m_s   = m_a + 16384;
    float* m_c   = m_s + 16384;
    float* att_a = m_c + 16384;
    float* att_s = att_a + 16384;
    float* att_c = att_s + 16384;

    hipLaunchKernelGGL(pool_kernel,   dim3(1024), dim3(256), 0, stream, x, ps, pc);
    hipLaunchKernelGGL(reduce_kernel, dim3(768),  dim3(256), 0, stream,
                       ps, pc, m_a, m_s, m_c);
    hipLaunchKernelGGL(attn_kernel,   dim3(192),  dim3(64),  0, stream,
                       m_a, m_s, m_c, w1_a, w1_s, w1_c, w2_a, w2_s, w2_c,
                       att_a, att_s, att_c);
    hipLaunchKernelGGL(scale_kernel,  dim3(2048), dim3(256), 0, stream,
                       x, att_a, att_s, att_c, out);
}